// Round 11
// baseline (284.023 us; speedup 1.0000x reference)
//
#include <hip/hip_runtime.h>
#include <hip/hip_fp16.h>

#define N_NODES 50000
#define N_EDGES 800000
#define N_GRAPHS 64

#define SCAN_BLOCK 256
#define SCAN_ITEMS 4
#define SCAN_CHUNK (SCAN_BLOCK * SCAN_ITEMS)                  // 1024
#define NB_SCAN ((N_NODES + SCAN_CHUNK - 1) / SCAN_CHUNK)     // 49

#define FILL_STRIPES 256   // blocks per node-range; grid = 8*FILL_STRIPES

struct __align__(8) h4v { __half2 a, b; };   // 4 fp16 features = 8 B

// ---------------- init ----------------

__global__ void k_zero(int* __restrict__ deg, float* __restrict__ sums) {
    int i = blockIdx.x * 256 + threadIdx.x;
    if (i < N_NODES) deg[i] = 0;
    if (i < N_GRAPHS * 128) sums[i] = 0.f;
}

// ---------------- CSR build ----------------

// XCD-partitioned degree count: deg[] lines stay XCD-local.
__global__ void k_deg_part(const int* __restrict__ dst, int* __restrict__ deg, int E) {
    const int range = blockIdx.x & 7;
    const int stripe = blockIdx.x >> 3;
    const int lo = range * (N_NODES / 8);
    const int hi = lo + (N_NODES / 8);
    for (int e = stripe * 256 + threadIdx.x; e < E; e += FILL_STRIPES * 256) {
        int d = dst[e];
        if (d >= lo && d < hi) atomicAdd(&deg[d], 1);
    }
}

// Exclusive scan of deg -> row_ptr/fill, dinv = rsqrt(deg+1).
// Each block self-computes its global prefix by reducing deg[0 .. b*CHUNK)
// (L2-resident, ~5 MB total across 49 blocks) — no separate partials kernel.
__global__ void k_scan(const int* __restrict__ deg,
                       int* __restrict__ row_ptr, int* __restrict__ fill,
                       float* __restrict__ dinv) {
    __shared__ int lds[SCAN_BLOCK];
    __shared__ int basePfxS;
    int b = blockIdx.x, t = threadIdx.x;
    int base = b * SCAN_CHUNK + t * SCAN_ITEMS;
    int v[SCAN_ITEMS];
    int s = 0;
#pragma unroll
    for (int k = 0; k < SCAN_ITEMS; ++k) {
        int i = base + k;
        v[k] = (i < N_NODES) ? deg[i] : 0;
        s += v[k];
    }
    // global prefix of this block's chunk
    int pre = 0;
    for (int i = t; i < b * SCAN_CHUNK; i += SCAN_BLOCK) pre += deg[i];
    lds[t] = pre;
    __syncthreads();
    for (int off = SCAN_BLOCK / 2; off > 0; off >>= 1) {
        if (t < off) lds[t] += lds[t + off];
        __syncthreads();
    }
    if (t == 0) basePfxS = lds[0];
    __syncthreads();
    int basePfx = basePfxS;
    __syncthreads();
    // intra-block scan over per-thread sums
    lds[t] = s;
    __syncthreads();
    for (int off = 1; off < SCAN_BLOCK; off <<= 1) {
        int val = (t >= off) ? lds[t - off] : 0;
        __syncthreads();
        lds[t] += val;
        __syncthreads();
    }
    int excl = (t == 0 ? 0 : lds[t - 1]) + basePfx;
#pragma unroll
    for (int k = 0; k < SCAN_ITEMS; ++k) {
        int i = base + k;
        if (i < N_NODES) {
            row_ptr[i] = excl;
            fill[i] = excl;
            dinv[i] = rsqrtf((float)(v[k] + 1));  // +1 self loop
            excl += v[k];
            if (i == N_NODES - 1) row_ptr[N_NODES] = excl;
        }
    }
}

// XCD-partitioned fill (R6 win). csr values ushort (src < 65536).
__global__ void k_fill_part(const int* __restrict__ src, const int* __restrict__ dst,
                            int* __restrict__ fill, unsigned short* __restrict__ csr, int E) {
    const int range = blockIdx.x & 7;
    const int stripe = blockIdx.x >> 3;
    const int lo = range * (N_NODES / 8);
    const int hi = lo + (N_NODES / 8);
    for (int e = stripe * 256 + threadIdx.x; e < E; e += FILL_STRIPES * 256) {
        int d = dst[e];
        if (d >= lo && d < hi) {
            int pos = atomicAdd(&fill[d], 1);
            csr[pos] = (unsigned short)src[e];
        }
    }
}

// ---------------- GEMM1: g̃(fp16) = dinv ⊙ (x @ W1) ----------------

__global__ __launch_bounds__(256) void k_gemm1(const float* __restrict__ A,
                                               const float* __restrict__ W,
                                               const float* __restrict__ dscale,
                                               __half* __restrict__ Cout, int N) {
    const int FIN = 128;
    __shared__ __align__(16) float As[64 * (FIN + 2)];
    __shared__ __align__(16) float Wsm[FIN * 64];
    const int t = threadIdx.x;
    const int row0 = blockIdx.x * 64;

    const int NF4 = 64 * FIN / 4;
    for (int idx = t; idx < NF4; idx += 256) {
        int r = idx / (FIN / 4);
        int c4 = idx % (FIN / 4);
        float4 v = make_float4(0.f, 0.f, 0.f, 0.f);
        if (row0 + r < N) v = ((const float4*)(A + (size_t)(row0 + r) * FIN))[c4];
        float* p = &As[r * (FIN + 2) + c4 * 4];
        ((float2*)p)[0] = make_float2(v.x, v.y);
        ((float2*)p)[1] = make_float2(v.z, v.w);
    }
    for (int idx = t; idx < FIN * 16; idx += 256) {
        int r = idx / 16, c4 = idx % 16;
        *((float4*)&Wsm[r * 64 + c4 * 4]) = ((const float4*)(W + (size_t)r * 64))[c4];
    }
    __syncthreads();

    const int tc = (t & 15) * 4;
    const int tr = (t >> 4) * 4;
    float acc[4][4] = {};
#pragma unroll 4
    for (int k = 0; k < FIN; k += 2) {
        float2 a[4];
#pragma unroll
        for (int r = 0; r < 4; ++r)
            a[r] = *(const float2*)&As[(tr + r) * (FIN + 2) + k];
        float4 w0 = *(const float4*)&Wsm[k * 64 + tc];
        float4 w1 = *(const float4*)&Wsm[(k + 1) * 64 + tc];
#pragma unroll
        for (int r = 0; r < 4; ++r) {
            acc[r][0] = fmaf(a[r].x, w0.x, acc[r][0]);
            acc[r][1] = fmaf(a[r].x, w0.y, acc[r][1]);
            acc[r][2] = fmaf(a[r].x, w0.z, acc[r][2]);
            acc[r][3] = fmaf(a[r].x, w0.w, acc[r][3]);
            acc[r][0] = fmaf(a[r].y, w1.x, acc[r][0]);
            acc[r][1] = fmaf(a[r].y, w1.y, acc[r][1]);
            acc[r][2] = fmaf(a[r].y, w1.z, acc[r][2]);
            acc[r][3] = fmaf(a[r].y, w1.w, acc[r][3]);
        }
    }

#pragma unroll
    for (int r = 0; r < 4; ++r) {
        int row = row0 + tr + r;
        if (row < N) {
            float s = dscale[row];
            __half2* dsth = (__half2*)(Cout + (size_t)row * 64 + tc);
            dsth[0] = __floats2half2_rn(acc[r][0] * s, acc[r][1] * s);
            dsth[1] = __floats2half2_rn(acc[r][2] * s, acc[r][3] * s);
        }
    }
}

// ---------------- aggregates: 16 lanes/node, 8 B per lane, 0 LDS ----------------
// h pre-scaled by dinv.
// RELU (conv1): out = fp16( dinv[n] * relu(bias + dinv[n]*sum) )   [h̃1]
// else (conv2): out = fp16( dinv[n] * sum )                         [z̃]

template <bool RELU>
__global__ void k_agg(const h4v* __restrict__ h, const float* __restrict__ dinv,
                      const int* __restrict__ row_ptr, const unsigned short* __restrict__ csr,
                      const float* __restrict__ bias, h4v* __restrict__ out, int N) {
    int node = blockIdx.x * 16 + (threadIdx.x >> 4);
    int lane = threadIdx.x & 15;
    if (node >= N) return;
    float di = dinv[node];
    h4v sv = h[(size_t)node * 16 + lane];  // self loop (pre-scaled)
    float2 pa = __half22float2(sv.a), pb = __half22float2(sv.b);
    float x0 = pa.x, y0 = pa.y, z0 = pb.x, w0 = pb.y;
    float x1 = 0, y1 = 0, z1 = 0, w1 = 0;
    float x2 = 0, y2 = 0, z2 = 0, w2 = 0;
    float x3 = 0, y3 = 0, z3 = 0, w3 = 0;
    int beg = row_ptr[node], end = row_ptr[node + 1];
    int j = beg;
    for (; j + 4 <= end; j += 4) {
        int s0 = csr[j], s1 = csr[j + 1], s2 = csr[j + 2], s3 = csr[j + 3];
        h4v v0 = h[(size_t)s0 * 16 + lane];
        h4v v1 = h[(size_t)s1 * 16 + lane];
        h4v v2 = h[(size_t)s2 * 16 + lane];
        h4v v3 = h[(size_t)s3 * 16 + lane];
        float2 a0 = __half22float2(v0.a), b0 = __half22float2(v0.b);
        float2 a1 = __half22float2(v1.a), b1 = __half22float2(v1.b);
        float2 a2 = __half22float2(v2.a), b2 = __half22float2(v2.b);
        float2 a3 = __half22float2(v3.a), b3 = __half22float2(v3.b);
        x0 += a0.x; y0 += a0.y; z0 += b0.x; w0 += b0.y;
        x1 += a1.x; y1 += a1.y; z1 += b1.x; w1 += b1.y;
        x2 += a2.x; y2 += a2.y; z2 += b2.x; w2 += b2.y;
        x3 += a3.x; y3 += a3.y; z3 += b3.x; w3 += b3.y;
    }
    for (; j < end; ++j) {
        h4v v = h[(size_t)csr[j] * 16 + lane];
        float2 a = __half22float2(v.a), b = __half22float2(v.b);
        x0 += a.x; y0 += a.y; z0 += b.x; w0 += b.y;
    }
    float sx = (x0 + x1) + (x2 + x3);
    float sy = (y0 + y1) + (y2 + y3);
    float sz = (z0 + z1) + (z2 + z3);
    float sw = (w0 + w1) + (w2 + w3);
    h4v o;
    if (RELU) {
        float4 bv = ((const float4*)bias)[lane];
        float vx = fmaf(sx, di, bv.x); vx = vx > 0.f ? vx : 0.f;
        float vy = fmaf(sy, di, bv.y); vy = vy > 0.f ? vy : 0.f;
        float vz = fmaf(sz, di, bv.z); vz = vz > 0.f ? vz : 0.f;
        float vw = fmaf(sw, di, bv.w); vw = vw > 0.f ? vw : 0.f;
        o.a = __floats2half2_rn(di * vx, di * vy);
        o.b = __floats2half2_rn(di * vz, di * vw);
    } else {
        o.a = __floats2half2_rn(sx * di, sy * di);
        o.b = __floats2half2_rn(sz * di, sw * di);
    }
    out[(size_t)node * 16 + lane] = o;
}

// ---------------- GEMM2 + mean-pool, single pass over all 128 cols ----------------
// h2 = relu(z̃@W2 + b2) never materialized; per-tile per-graph LDS reduce + atomics.

__global__ __launch_bounds__(256) void k_gemm_pool(const __half2* __restrict__ A2,
                                                   const float* __restrict__ W,
                                                   const float* __restrict__ bias,
                                                   const int* __restrict__ batch,
                                                   float* __restrict__ sums, int N) {
    __shared__ __align__(16) float As[64 * 66];      // z tile fp32; reused as red[16][132]
    __shared__ __align__(16) float Wsm[64 * 128];
    __shared__ int batchLDS[64];
    const int t = threadIdx.x;
    const int row0 = blockIdx.x * 64;
    const int grp = t >> 4, lane = t & 15;

    // stage A (fp16 -> fp32): 64 rows x 32 half2
    for (int idx = t; idx < 64 * 32; idx += 256) {
        int r = idx >> 5, c2 = idx & 31;
        float2 v = make_float2(0.f, 0.f);
        if (row0 + r < N) v = __half22float2(A2[(size_t)(row0 + r) * 32 + c2]);
        *(float2*)&As[r * 66 + c2 * 2] = v;
    }
    // stage full W2 (64 x 128)
    for (int idx = t; idx < 64 * 32; idx += 256) {
        int r = idx >> 5, c4 = idx & 31;
        *(float4*)&Wsm[r * 128 + c4 * 4] = *(const float4*)&W[(size_t)r * 128 + c4 * 4];
    }
    if (t < 64) batchLDS[t] = batch[min(row0 + t, N - 1)];
    __syncthreads();

    const int tc = lane * 4;   // cols [tc, tc+4) and [64+tc, 64+tc+4)
    const int tr = grp * 4;
    float acc[4][8] = {};
#pragma unroll 2
    for (int k = 0; k < 64; k += 2) {
        float2 a[4];
#pragma unroll
        for (int r = 0; r < 4; ++r)
            a[r] = *(const float2*)&As[(tr + r) * 66 + k];
        float4 wa0 = *(const float4*)&Wsm[k * 128 + tc];
        float4 wb0 = *(const float4*)&Wsm[k * 128 + 64 + tc];
        float4 wa1 = *(const float4*)&Wsm[(k + 1) * 128 + tc];
        float4 wb1 = *(const float4*)&Wsm[(k + 1) * 128 + 64 + tc];
#pragma unroll
        for (int r = 0; r < 4; ++r) {
            acc[r][0] = fmaf(a[r].x, wa0.x, acc[r][0]);
            acc[r][1] = fmaf(a[r].x, wa0.y, acc[r][1]);
            acc[r][2] = fmaf(a[r].x, wa0.z, acc[r][2]);
            acc[r][3] = fmaf(a[r].x, wa0.w, acc[r][3]);
            acc[r][4] = fmaf(a[r].x, wb0.x, acc[r][4]);
            acc[r][5] = fmaf(a[r].x, wb0.y, acc[r][5]);
            acc[r][6] = fmaf(a[r].x, wb0.z, acc[r][6]);
            acc[r][7] = fmaf(a[r].x, wb0.w, acc[r][7]);
            acc[r][0] = fmaf(a[r].y, wa1.x, acc[r][0]);
            acc[r][1] = fmaf(a[r].y, wa1.y, acc[r][1]);
            acc[r][2] = fmaf(a[r].y, wa1.z, acc[r][2]);
            acc[r][3] = fmaf(a[r].y, wa1.w, acc[r][3]);
            acc[r][4] = fmaf(a[r].y, wb1.x, acc[r][4]);
            acc[r][5] = fmaf(a[r].y, wb1.y, acc[r][5]);
            acc[r][6] = fmaf(a[r].y, wb1.z, acc[r][6]);
            acc[r][7] = fmaf(a[r].y, wb1.w, acc[r][7]);
        }
    }

    // bias + relu; invalid rows contribute 0
    float4 bva = *(const float4*)&bias[tc];
    float4 bvb = *(const float4*)&bias[64 + tc];
    float v[4][8];
#pragma unroll
    for (int r = 0; r < 4; ++r) {
        bool valid = (row0 + tr + r) < N;
        v[r][0] = valid ? fmaxf(acc[r][0] + bva.x, 0.f) : 0.f;
        v[r][1] = valid ? fmaxf(acc[r][1] + bva.y, 0.f) : 0.f;
        v[r][2] = valid ? fmaxf(acc[r][2] + bva.z, 0.f) : 0.f;
        v[r][3] = valid ? fmaxf(acc[r][3] + bva.w, 0.f) : 0.f;
        v[r][4] = valid ? fmaxf(acc[r][4] + bvb.x, 0.f) : 0.f;
        v[r][5] = valid ? fmaxf(acc[r][5] + bvb.y, 0.f) : 0.f;
        v[r][6] = valid ? fmaxf(acc[r][6] + bvb.z, 0.f) : 0.f;
        v[r][7] = valid ? fmaxf(acc[r][7] + bvb.w, 0.f) : 0.f;
    }

    __syncthreads();  // done with As as GEMM input; reuse as red[16][132]
    float* red = As;
    const int g0 = batchLDS[0], g1 = batchLDS[63];
    for (int g = g0; g <= g1; ++g) {
        float p[8] = {};
#pragma unroll
        for (int r = 0; r < 4; ++r) {
            if (batchLDS[tr + r] == g) {
#pragma unroll
                for (int c = 0; c < 8; ++c) p[c] += v[r][c];
            }
        }
        *(float4*)&red[grp * 132 + tc] = make_float4(p[0], p[1], p[2], p[3]);
        *(float4*)&red[grp * 132 + 64 + tc] = make_float4(p[4], p[5], p[6], p[7]);
        __syncthreads();
        for (int off = 8; off > 0; off >>= 1) {
            if (grp < off) {
#pragma unroll
                for (int c = 0; c < 4; ++c) {
                    red[grp * 132 + tc + c] += red[(grp + off) * 132 + tc + c];
                    red[grp * 132 + 64 + tc + c] += red[(grp + off) * 132 + 64 + tc + c];
                }
            }
            __syncthreads();
        }
        if (t < 32) {
#pragma unroll
            for (int c = 0; c < 4; ++c)
                atomicAdd(&sums[g * 128 + t * 4 + c], red[t * 4 + c]);
        }
        __syncthreads();
    }
}

// ---------------- MLP head: one block per graph (cnt via binary search) ----------------

__global__ void k_mlp(const float* __restrict__ sums, const int* __restrict__ batch, int N,
                      const float* __restrict__ M1, const float* __restrict__ c1,
                      const float* __restrict__ M2, const float* __restrict__ c2,
                      const float* __restrict__ M3, const float* __restrict__ c3,
                      const float* __restrict__ M4, const float* __restrict__ c4,
                      float* __restrict__ out) {
    __shared__ float g[128], t1[64], t2[64], t3[64];
    __shared__ float cntb;
    int b = blockIdx.x;
    int t = threadIdx.x;
    if (t == 0) {
        int lo = 0, hi = N;
        while (lo < hi) { int m = (lo + hi) >> 1; if (batch[m] < b) lo = m + 1; else hi = m; }
        int lb = lo;
        lo = 0; hi = N;
        while (lo < hi) { int m = (lo + hi) >> 1; if (batch[m] <= b) lo = m + 1; else hi = m; }
        cntb = fmaxf((float)(lo - lb), 1.0f);
    }
    __syncthreads();
    if (t < 128) g[t] = sums[b * 128 + t] / cntb;
    __syncthreads();
    if (t < 64) {
        float acc = c1[t];
        for (int k = 0; k < 128; ++k) acc = fmaf(g[k], M1[k * 64 + t], acc);
        t1[t] = acc >= 0.f ? acc : 0.2f * acc;
    }
    __syncthreads();
    if (t < 64) {
        float acc = c2[t];
        for (int k = 0; k < 64; ++k) acc = fmaf(t1[k], M2[k * 64 + t], acc);
        t2[t] = acc >= 0.f ? acc : 0.1f * acc;
    }
    __syncthreads();
    if (t < 64) {
        float acc = c3[t];
        for (int k = 0; k < 64; ++k) acc = fmaf(t2[k], M3[k * 64 + t], acc);
        t3[t] = acc >= 0.f ? acc : 0.1f * acc;
    }
    __syncthreads();
    if (t == 0) {
        float acc = c4[0];
        for (int k = 0; k < 64; ++k) acc = fmaf(t3[k], M4[k], acc);
        out[b] = fmaxf(acc, 0.f);
    }
}

// ---------------- launch ----------------

extern "C" void kernel_launch(void* const* d_in, const int* in_sizes, int n_in,
                              void* d_out, int out_size, void* d_ws, size_t ws_size,
                              hipStream_t stream) {
    const float* x   = (const float*)d_in[0];
    const int*   ei  = (const int*)d_in[1];
    const int*   bat = (const int*)d_in[2];
    const float* W1  = (const float*)d_in[3];
    const float* b1  = (const float*)d_in[4];
    const float* W2  = (const float*)d_in[5];
    const float* b2  = (const float*)d_in[6];
    const float* M1  = (const float*)d_in[7];
    const float* c1  = (const float*)d_in[8];
    const float* M2  = (const float*)d_in[9];
    const float* c2  = (const float*)d_in[10];
    const float* M3  = (const float*)d_in[11];
    const float* c3  = (const float*)d_in[12];
    const float* M4  = (const float*)d_in[13];
    const float* c4  = (const float*)d_in[14];
    float* out = (float*)d_out;

    const int* src = ei;            // edge_index[0]
    const int* dst = ei + N_EDGES;  // edge_index[1]

    // workspace layout
    float* bufA    = (float*)d_ws;                          // g̃ / z̃: N*64 fp16
    float* bufB    = bufA + (size_t)N_NODES * 64;           // h̃1: N*64 fp16
    float* dinv    = bufB + (size_t)N_NODES * 64;           // N f
    float* sums    = dinv + N_NODES;                        // 64*128 f
    int*   deg     = (int*)(sums + N_GRAPHS * 128);         // N i
    int*   row_ptr = deg + N_NODES;                         // N+1 i
    int*   fill    = row_ptr + N_NODES + 1;                 // N i
    unsigned short* csr = (unsigned short*)(fill + N_NODES); // E u16

    // ---- init + CSR build + normalization ----
    k_zero<<<(N_NODES + 255) / 256, 256, 0, stream>>>(deg, sums);
    k_deg_part<<<8 * FILL_STRIPES, 256, 0, stream>>>(dst, deg, N_EDGES);
    k_scan<<<NB_SCAN, SCAN_BLOCK, 0, stream>>>(deg, row_ptr, fill, dinv);
    k_fill_part<<<8 * FILL_STRIPES, 256, 0, stream>>>(src, dst, fill, csr, N_EDGES);

    const int NBLK = (N_NODES + 63) / 64;   // 782
    const int ABLK = (N_NODES + 15) / 16;   // 3125

    // ---- conv1: g̃(fp16) = dinv ⊙ (x@W1); h̃1(fp16) = dinv ⊙ relu(Â-sum + b1) ----
    k_gemm1<<<NBLK, 256, 0, stream>>>(x, W1, dinv, (__half*)bufA, N_NODES);
    k_agg<true><<<ABLK, 256, 0, stream>>>(
        (const h4v*)bufA, dinv, row_ptr, csr, b1, (h4v*)bufB, N_NODES);

    // ---- conv2: z̃(fp16) = dinv ⊙ (Σ h̃1); single-pass gemm2+relu+mean-pool ----
    k_agg<false><<<ABLK, 256, 0, stream>>>(
        (const h4v*)bufB, dinv, row_ptr, csr, nullptr, (h4v*)bufA, N_NODES);
    k_gemm_pool<<<NBLK, 256, 0, stream>>>(
        (const __half2*)bufA, W2, b2, bat, sums, N_NODES);

    // ---- MLP ----
    k_mlp<<<N_GRAPHS, 128, 0, stream>>>(sums, bat, N_NODES,
                                        M1, c1, M2, c2, M3, c3, M4, c4, out);
}

// Round 12
// 282.478 us; speedup vs baseline: 1.0055x; 1.0055x over previous
//
#include <hip/hip_runtime.h>
#include <hip/hip_fp16.h>

#define N_NODES 50000
#define N_EDGES 800000
#define N_GRAPHS 64

#define SCAN_BLOCK 256
#define SCAN_ITEMS 4
#define SCAN_CHUNK (SCAN_BLOCK * SCAN_ITEMS)                  // 1024
#define NB_SCAN ((N_NODES + SCAN_CHUNK - 1) / SCAN_CHUNK)     // 49

#define FILL_STRIPES 256   // blocks per node-range; grid = 8*FILL_STRIPES

struct __align__(8) h4v { __half2 a, b; };   // 4 fp16 features = 8 B

// ---------------- init ----------------

__global__ void k_zero(int* __restrict__ deg, float* __restrict__ sums) {
    int i = blockIdx.x * 256 + threadIdx.x;
    if (i < N_NODES) deg[i] = 0;
    if (i < N_GRAPHS * 128) sums[i] = 0.f;
}

// ---------------- CSR build ----------------

// XCD-partitioned degree count: deg[] lines stay XCD-local.
__global__ void k_deg_part(const int* __restrict__ dst, int* __restrict__ deg, int E) {
    const int range = blockIdx.x & 7;
    const int stripe = blockIdx.x >> 3;
    const int lo = range * (N_NODES / 8);
    const int hi = lo + (N_NODES / 8);
    for (int e = stripe * 256 + threadIdx.x; e < E; e += FILL_STRIPES * 256) {
        int d = dst[e];
        if (d >= lo && d < hi) atomicAdd(&deg[d], 1);
    }
}

// Exclusive scan of deg -> row_ptr/fill, dinv = rsqrt(deg+1).
// Each block self-computes its global prefix (L2-resident reads) — single kernel.
__global__ void k_scan(const int* __restrict__ deg,
                       int* __restrict__ row_ptr, int* __restrict__ fill,
                       float* __restrict__ dinv) {
    __shared__ int lds[SCAN_BLOCK];
    __shared__ int basePfxS;
    int b = blockIdx.x, t = threadIdx.x;
    int base = b * SCAN_CHUNK + t * SCAN_ITEMS;
    int v[SCAN_ITEMS];
    int s = 0;
#pragma unroll
    for (int k = 0; k < SCAN_ITEMS; ++k) {
        int i = base + k;
        v[k] = (i < N_NODES) ? deg[i] : 0;
        s += v[k];
    }
    int pre = 0;
    for (int i = t; i < b * SCAN_CHUNK; i += SCAN_BLOCK) pre += deg[i];
    lds[t] = pre;
    __syncthreads();
    for (int off = SCAN_BLOCK / 2; off > 0; off >>= 1) {
        if (t < off) lds[t] += lds[t + off];
        __syncthreads();
    }
    if (t == 0) basePfxS = lds[0];
    __syncthreads();
    int basePfx = basePfxS;
    __syncthreads();
    lds[t] = s;
    __syncthreads();
    for (int off = 1; off < SCAN_BLOCK; off <<= 1) {
        int val = (t >= off) ? lds[t - off] : 0;
        __syncthreads();
        lds[t] += val;
        __syncthreads();
    }
    int excl = (t == 0 ? 0 : lds[t - 1]) + basePfx;
#pragma unroll
    for (int k = 0; k < SCAN_ITEMS; ++k) {
        int i = base + k;
        if (i < N_NODES) {
            row_ptr[i] = excl;
            fill[i] = excl;
            dinv[i] = rsqrtf((float)(v[k] + 1));  // +1 self loop
            excl += v[k];
            if (i == N_NODES - 1) row_ptr[N_NODES] = excl;
        }
    }
}

// XCD-partitioned fill (R6 win). csr values ushort (src < 65536).
__global__ void k_fill_part(const int* __restrict__ src, const int* __restrict__ dst,
                            int* __restrict__ fill, unsigned short* __restrict__ csr, int E) {
    const int range = blockIdx.x & 7;
    const int stripe = blockIdx.x >> 3;
    const int lo = range * (N_NODES / 8);
    const int hi = lo + (N_NODES / 8);
    for (int e = stripe * 256 + threadIdx.x; e < E; e += FILL_STRIPES * 256) {
        int d = dst[e];
        if (d >= lo && d < hi) {
            int pos = atomicAdd(&fill[d], 1);
            csr[pos] = (unsigned short)src[e];
        }
    }
}

// ---------------- GEMM1: g̃(fp16) = dinv ⊙ (x @ W1) ----------------

__global__ __launch_bounds__(256) void k_gemm1(const float* __restrict__ A,
                                               const float* __restrict__ W,
                                               const float* __restrict__ dscale,
                                               __half* __restrict__ Cout, int N) {
    const int FIN = 128;
    __shared__ __align__(16) float As[64 * (FIN + 2)];
    __shared__ __align__(16) float Wsm[FIN * 64];
    const int t = threadIdx.x;
    const int row0 = blockIdx.x * 64;

    const int NF4 = 64 * FIN / 4;
    for (int idx = t; idx < NF4; idx += 256) {
        int r = idx / (FIN / 4);
        int c4 = idx % (FIN / 4);
        float4 v = make_float4(0.f, 0.f, 0.f, 0.f);
        if (row0 + r < N) v = ((const float4*)(A + (size_t)(row0 + r) * FIN))[c4];
        float* p = &As[r * (FIN + 2) + c4 * 4];
        ((float2*)p)[0] = make_float2(v.x, v.y);
        ((float2*)p)[1] = make_float2(v.z, v.w);
    }
    for (int idx = t; idx < FIN * 16; idx += 256) {
        int r = idx / 16, c4 = idx % 16;
        *((float4*)&Wsm[r * 64 + c4 * 4]) = ((const float4*)(W + (size_t)r * 64))[c4];
    }
    __syncthreads();

    const int tc = (t & 15) * 4;
    const int tr = (t >> 4) * 4;
    float acc[4][4] = {};
#pragma unroll 4
    for (int k = 0; k < FIN; k += 2) {
        float2 a[4];
#pragma unroll
        for (int r = 0; r < 4; ++r)
            a[r] = *(const float2*)&As[(tr + r) * (FIN + 2) + k];
        float4 w0 = *(const float4*)&Wsm[k * 64 + tc];
        float4 w1 = *(const float4*)&Wsm[(k + 1) * 64 + tc];
#pragma unroll
        for (int r = 0; r < 4; ++r) {
            acc[r][0] = fmaf(a[r].x, w0.x, acc[r][0]);
            acc[r][1] = fmaf(a[r].x, w0.y, acc[r][1]);
            acc[r][2] = fmaf(a[r].x, w0.z, acc[r][2]);
            acc[r][3] = fmaf(a[r].x, w0.w, acc[r][3]);
            acc[r][0] = fmaf(a[r].y, w1.x, acc[r][0]);
            acc[r][1] = fmaf(a[r].y, w1.y, acc[r][1]);
            acc[r][2] = fmaf(a[r].y, w1.z, acc[r][2]);
            acc[r][3] = fmaf(a[r].y, w1.w, acc[r][3]);
        }
    }

#pragma unroll
    for (int r = 0; r < 4; ++r) {
        int row = row0 + tr + r;
        if (row < N) {
            float s = dscale[row];
            __half2* dsth = (__half2*)(Cout + (size_t)row * 64 + tc);
            dsth[0] = __floats2half2_rn(acc[r][0] * s, acc[r][1] * s);
            dsth[1] = __floats2half2_rn(acc[r][2] * s, acc[r][3] * s);
        }
    }
}

// ---------------- aggregates: 16 lanes/node, 8 B per lane, 0 LDS ----------------
// h pre-scaled by dinv.
// RELU (conv1): out = fp16( dinv[n] * relu(bias + dinv[n]*sum) )   [h̃1]
// else (conv2): out = fp16( dinv[n] * sum )                         [z̃]

template <bool RELU>
__global__ void k_agg(const h4v* __restrict__ h, const float* __restrict__ dinv,
                      const int* __restrict__ row_ptr, const unsigned short* __restrict__ csr,
                      const float* __restrict__ bias, h4v* __restrict__ out, int N) {
    int node = blockIdx.x * 16 + (threadIdx.x >> 4);
    int lane = threadIdx.x & 15;
    if (node >= N) return;
    float di = dinv[node];
    h4v sv = h[(size_t)node * 16 + lane];  // self loop (pre-scaled)
    float2 pa = __half22float2(sv.a), pb = __half22float2(sv.b);
    float x0 = pa.x, y0 = pa.y, z0 = pb.x, w0 = pb.y;
    float x1 = 0, y1 = 0, z1 = 0, w1 = 0;
    float x2 = 0, y2 = 0, z2 = 0, w2 = 0;
    float x3 = 0, y3 = 0, z3 = 0, w3 = 0;
    int beg = row_ptr[node], end = row_ptr[node + 1];
    int j = beg;
    for (; j + 4 <= end; j += 4) {
        int s0 = csr[j], s1 = csr[j + 1], s2 = csr[j + 2], s3 = csr[j + 3];
        h4v v0 = h[(size_t)s0 * 16 + lane];
        h4v v1 = h[(size_t)s1 * 16 + lane];
        h4v v2 = h[(size_t)s2 * 16 + lane];
        h4v v3 = h[(size_t)s3 * 16 + lane];
        float2 a0 = __half22float2(v0.a), b0 = __half22float2(v0.b);
        float2 a1 = __half22float2(v1.a), b1 = __half22float2(v1.b);
        float2 a2 = __half22float2(v2.a), b2 = __half22float2(v2.b);
        float2 a3 = __half22float2(v3.a), b3 = __half22float2(v3.b);
        x0 += a0.x; y0 += a0.y; z0 += b0.x; w0 += b0.y;
        x1 += a1.x; y1 += a1.y; z1 += b1.x; w1 += b1.y;
        x2 += a2.x; y2 += a2.y; z2 += b2.x; w2 += b2.y;
        x3 += a3.x; y3 += a3.y; z3 += b3.x; w3 += b3.y;
    }
    for (; j < end; ++j) {
        h4v v = h[(size_t)csr[j] * 16 + lane];
        float2 a = __half22float2(v.a), b = __half22float2(v.b);
        x0 += a.x; y0 += a.y; z0 += b.x; w0 += b.y;
    }
    float sx = (x0 + x1) + (x2 + x3);
    float sy = (y0 + y1) + (y2 + y3);
    float sz = (z0 + z1) + (z2 + z3);
    float sw = (w0 + w1) + (w2 + w3);
    h4v o;
    if (RELU) {
        float4 bv = ((const float4*)bias)[lane];
        float vx = fmaf(sx, di, bv.x); vx = vx > 0.f ? vx : 0.f;
        float vy = fmaf(sy, di, bv.y); vy = vy > 0.f ? vy : 0.f;
        float vz = fmaf(sz, di, bv.z); vz = vz > 0.f ? vz : 0.f;
        float vw = fmaf(sw, di, bv.w); vw = vw > 0.f ? vw : 0.f;
        o.a = __floats2half2_rn(di * vx, di * vy);
        o.b = __floats2half2_rn(di * vz, di * vw);
    } else {
        o.a = __floats2half2_rn(sx * di, sy * di);
        o.b = __floats2half2_rn(sz * di, sw * di);
    }
    out[(size_t)node * 16 + lane] = o;
}

// ---------------- GEMM2 fused with mean-pool (R10 two-pass structure) ----------------
// h2 = relu(z̃@W2 + b2) never materialized; per-tile per-graph LDS reduce + atomics.

__global__ __launch_bounds__(256) void k_gemm_pool(const __half2* __restrict__ A2,
                                                   const float* __restrict__ W,
                                                   const float* __restrict__ bias,
                                                   const int* __restrict__ batch,
                                                   float* __restrict__ sums, int N) {
    __shared__ __align__(16) float As[64 * 66];
    __shared__ __align__(16) float Wsm[64 * 64];
    __shared__ float red[16][68];
    __shared__ int batchLDS[64];
    const int t = threadIdx.x;
    const int row0 = blockIdx.x * 64;
    const int coff = blockIdx.y * 64;

    // stage A (fp16 -> fp32): 64 rows x 32 half2
    for (int idx = t; idx < 64 * 32; idx += 256) {
        int r = idx >> 5, c2 = idx & 31;
        float2 v = make_float2(0.f, 0.f);
        if (row0 + r < N) v = __half22float2(A2[(size_t)(row0 + r) * 32 + c2]);
        *(float2*)&As[r * 66 + c2 * 2] = v;
    }
    // stage W col slice (64 x 64 of [64,128])
    for (int idx = t; idx < 64 * 16; idx += 256) {
        int r = idx >> 4, c4 = idx & 15;
        *(float4*)&Wsm[r * 64 + c4 * 4] = *(const float4*)&W[(size_t)r * 128 + coff + c4 * 4];
    }
    if (t < 64) batchLDS[t] = batch[min(row0 + t, N - 1)];
    __syncthreads();

    const int tc = (t & 15) * 4;
    const int tr = (t >> 4) * 4;
    float acc[4][4] = {};
#pragma unroll 4
    for (int k = 0; k < 64; k += 2) {
        float2 a[4];
#pragma unroll
        for (int r = 0; r < 4; ++r)
            a[r] = *(const float2*)&As[(tr + r) * 66 + k];
        float4 w0 = *(const float4*)&Wsm[k * 64 + tc];
        float4 w1 = *(const float4*)&Wsm[(k + 1) * 64 + tc];
#pragma unroll
        for (int r = 0; r < 4; ++r) {
            acc[r][0] = fmaf(a[r].x, w0.x, acc[r][0]);
            acc[r][1] = fmaf(a[r].x, w0.y, acc[r][1]);
            acc[r][2] = fmaf(a[r].x, w0.z, acc[r][2]);
            acc[r][3] = fmaf(a[r].x, w0.w, acc[r][3]);
            acc[r][0] = fmaf(a[r].y, w1.x, acc[r][0]);
            acc[r][1] = fmaf(a[r].y, w1.y, acc[r][1]);
            acc[r][2] = fmaf(a[r].y, w1.z, acc[r][2]);
            acc[r][3] = fmaf(a[r].y, w1.w, acc[r][3]);
        }
    }

    // bias + relu; invalid rows contribute 0
    float4 bv = *(const float4*)&bias[coff + tc];
    float v[4][4];
#pragma unroll
    for (int r = 0; r < 4; ++r) {
        bool valid = (row0 + tr + r) < N;
        v[r][0] = valid ? fmaxf(acc[r][0] + bv.x, 0.f) : 0.f;
        v[r][1] = valid ? fmaxf(acc[r][1] + bv.y, 0.f) : 0.f;
        v[r][2] = valid ? fmaxf(acc[r][2] + bv.z, 0.f) : 0.f;
        v[r][3] = valid ? fmaxf(acc[r][3] + bv.w, 0.f) : 0.f;
    }

    const int g0 = batchLDS[0], g1 = batchLDS[63];
    const int trg = t >> 4;
    for (int g = g0; g <= g1; ++g) {
        float p0 = 0.f, p1 = 0.f, p2 = 0.f, p3 = 0.f;
#pragma unroll
        for (int r = 0; r < 4; ++r) {
            if (batchLDS[tr + r] == g) { p0 += v[r][0]; p1 += v[r][1]; p2 += v[r][2]; p3 += v[r][3]; }
        }
        red[trg][tc + 0] = p0; red[trg][tc + 1] = p1;
        red[trg][tc + 2] = p2; red[trg][tc + 3] = p3;
        __syncthreads();
        for (int off = 8; off > 0; off >>= 1) {
            if (trg < off) {
#pragma unroll
                for (int c = 0; c < 4; ++c) red[trg][tc + c] += red[trg + off][tc + c];
            }
            __syncthreads();
        }
        if (t < 16) {
#pragma unroll
            for (int c = 0; c < 4; ++c)
                atomicAdd(&sums[g * 128 + coff + t * 4 + c], red[0][t * 4 + c]);
        }
        __syncthreads();
    }
}

// ---------------- MLP head: one block per graph (cnt via binary search) ----------------

__global__ void k_mlp(const float* __restrict__ sums, const int* __restrict__ batch, int N,
                      const float* __restrict__ M1, const float* __restrict__ c1,
                      const float* __restrict__ M2, const float* __restrict__ c2,
                      const float* __restrict__ M3, const float* __restrict__ c3,
                      const float* __restrict__ M4, const float* __restrict__ c4,
                      float* __restrict__ out) {
    __shared__ float g[128], t1[64], t2[64], t3[64];
    __shared__ float cntb;
    int b = blockIdx.x;
    int t = threadIdx.x;
    if (t == 0) {
        int lo = 0, hi = N;
        while (lo < hi) { int m = (lo + hi) >> 1; if (batch[m] < b) lo = m + 1; else hi = m; }
        int lb = lo;
        lo = 0; hi = N;
        while (lo < hi) { int m = (lo + hi) >> 1; if (batch[m] <= b) lo = m + 1; else hi = m; }
        cntb = fmaxf((float)(lo - lb), 1.0f);
    }
    __syncthreads();
    if (t < 128) g[t] = sums[b * 128 + t] / cntb;
    __syncthreads();
    if (t < 64) {
        float acc = c1[t];
        for (int k = 0; k < 128; ++k) acc = fmaf(g[k], M1[k * 64 + t], acc);
        t1[t] = acc >= 0.f ? acc : 0.2f * acc;
    }
    __syncthreads();
    if (t < 64) {
        float acc = c2[t];
        for (int k = 0; k < 64; ++k) acc = fmaf(t1[k], M2[k * 64 + t], acc);
        t2[t] = acc >= 0.f ? acc : 0.1f * acc;
    }
    __syncthreads();
    if (t < 64) {
        float acc = c3[t];
        for (int k = 0; k < 64; ++k) acc = fmaf(t2[k], M3[k * 64 + t], acc);
        t3[t] = acc >= 0.f ? acc : 0.1f * acc;
    }
    __syncthreads();
    if (t == 0) {
        float acc = c4[0];
        for (int k = 0; k < 64; ++k) acc = fmaf(t3[k], M4[k], acc);
        out[b] = fmaxf(acc, 0.f);
    }
}

// ---------------- launch ----------------

extern "C" void kernel_launch(void* const* d_in, const int* in_sizes, int n_in,
                              void* d_out, int out_size, void* d_ws, size_t ws_size,
                              hipStream_t stream) {
    const float* x   = (const float*)d_in[0];
    const int*   ei  = (const int*)d_in[1];
    const int*   bat = (const int*)d_in[2];
    const float* W1  = (const float*)d_in[3];
    const float* b1  = (const float*)d_in[4];
    const float* W2  = (const float*)d_in[5];
    const float* b2  = (const float*)d_in[6];
    const float* M1  = (const float*)d_in[7];
    const float* c1  = (const float*)d_in[8];
    const float* M2  = (const float*)d_in[9];
    const float* c2  = (const float*)d_in[10];
    const float* M3  = (const float*)d_in[11];
    const float* c3  = (const float*)d_in[12];
    const float* M4  = (const float*)d_in[13];
    const float* c4  = (const float*)d_in[14];
    float* out = (float*)d_out;

    const int* src = ei;            // edge_index[0]
    const int* dst = ei + N_EDGES;  // edge_index[1]

    // workspace layout
    float* bufA    = (float*)d_ws;                          // g̃ / z̃: N*64 fp16
    float* bufB    = bufA + (size_t)N_NODES * 64;           // h̃1: N*64 fp16
    float* dinv    = bufB + (size_t)N_NODES * 64;           // N f
    float* sums    = dinv + N_NODES;                        // 64*128 f
    int*   deg     = (int*)(sums + N_GRAPHS * 128);         // N i
    int*   row_ptr = deg + N_NODES;                         // N+1 i
    int*   fill    = row_ptr + N_NODES + 1;                 // N i
    unsigned short* csr = (unsigned short*)(fill + N_NODES); // E u16

    // ---- init + CSR build + normalization ----
    k_zero<<<(N_NODES + 255) / 256, 256, 0, stream>>>(deg, sums);
    k_deg_part<<<8 * FILL_STRIPES, 256, 0, stream>>>(dst, deg, N_EDGES);
    k_scan<<<NB_SCAN, SCAN_BLOCK, 0, stream>>>(deg, row_ptr, fill, dinv);
    k_fill_part<<<8 * FILL_STRIPES, 256, 0, stream>>>(src, dst, fill, csr, N_EDGES);

    const int NBLK = (N_NODES + 63) / 64;   // 782
    const int ABLK = (N_NODES + 15) / 16;   // 3125

    // ---- conv1: g̃(fp16) = dinv ⊙ (x@W1); h̃1(fp16) = dinv ⊙ relu(Â-sum + b1) ----
    k_gemm1<<<NBLK, 256, 0, stream>>>(x, W1, dinv, (__half*)bufA, N_NODES);
    k_agg<true><<<ABLK, 256, 0, stream>>>(
        (const h4v*)bufA, dinv, row_ptr, csr, b1, (h4v*)bufB, N_NODES);

    // ---- conv2: z̃(fp16) = dinv ⊙ (Σ h̃1); two-pass gemm2+relu+mean-pool ----
    k_agg<false><<<ABLK, 256, 0, stream>>>(
        (const h4v*)bufB, dinv, row_ptr, csr, nullptr, (h4v*)bufA, N_NODES);
    k_gemm_pool<<<dim3(NBLK, 2), 256, 0, stream>>>(
        (const __half2*)bufA, W2, b2, bat, sums, N_NODES);

    // ---- MLP ----
    k_mlp<<<N_GRAPHS, 128, 0, stream>>>(sums, bat, N_NODES,
                                        M1, c1, M2, c2, M3, c3, M4, c4, out);
}

// Round 13
// 261.206 us; speedup vs baseline: 1.0874x; 1.0814x over previous
//
#include <hip/hip_runtime.h>
#include <hip/hip_fp16.h>

#define N_NODES 50000
#define N_EDGES 800000
#define N_GRAPHS 64

#define SCAN_BLOCK 256
#define SCAN_ITEMS 4
#define SCAN_CHUNK (SCAN_BLOCK * SCAN_ITEMS)                  // 1024
#define NB_SCAN ((N_NODES + SCAN_CHUNK - 1) / SCAN_CHUNK)     // 49

#define FILL_STRIPES 256   // blocks per node-range; grid = 8*FILL_STRIPES

struct __align__(8) h4v { __half2 a, b; };   // 4 fp16 features = 8 B

// ---------------- init ----------------

__global__ void k_zero(int* __restrict__ deg, float* __restrict__ sums) {
    int i = blockIdx.x * 256 + threadIdx.x;
    if (i < N_NODES) deg[i] = 0;
    if (i < N_GRAPHS * 128) sums[i] = 0.f;
}

// ---------------- CSR build ----------------

// XCD-partitioned degree count: deg[] lines stay XCD-local.
__global__ void k_deg_part(const int* __restrict__ dst, int* __restrict__ deg, int E) {
    const int range = blockIdx.x & 7;
    const int stripe = blockIdx.x >> 3;
    const int lo = range * (N_NODES / 8);
    const int hi = lo + (N_NODES / 8);
    for (int e = stripe * 256 + threadIdx.x; e < E; e += FILL_STRIPES * 256) {
        int d = dst[e];
        if (d >= lo && d < hi) atomicAdd(&deg[d], 1);
    }
}

__global__ void k_scan1(const int* __restrict__ deg, int* __restrict__ part) {
    __shared__ int lds[SCAN_BLOCK];
    int b = blockIdx.x, t = threadIdx.x;
    int base = b * SCAN_CHUNK + t * SCAN_ITEMS;
    int s = 0;
#pragma unroll
    for (int k = 0; k < SCAN_ITEMS; ++k) {
        int i = base + k;
        if (i < N_NODES) s += deg[i];
    }
    lds[t] = s;
    __syncthreads();
    for (int off = SCAN_BLOCK / 2; off > 0; off >>= 1) {
        if (t < off) lds[t] += lds[t + off];
        __syncthreads();
    }
    if (t == 0) part[b] = lds[0];
}

// scan3 with scan2 folded in: each block computes its own prefix over part[].
__global__ void k_scan3(const int* __restrict__ deg, const int* __restrict__ part,
                        int* __restrict__ row_ptr, int* __restrict__ fill,
                        float* __restrict__ dinv) {
    __shared__ int lds[SCAN_BLOCK];
    __shared__ int pl[64];
    __shared__ int basePfx;
    int b = blockIdx.x, t = threadIdx.x;
    if (t < NB_SCAN) pl[t] = part[t];
    int base = b * SCAN_CHUNK + t * SCAN_ITEMS;
    int v[SCAN_ITEMS];
    int s = 0;
#pragma unroll
    for (int k = 0; k < SCAN_ITEMS; ++k) {
        int i = base + k;
        v[k] = (i < N_NODES) ? deg[i] : 0;
        s += v[k];
    }
    lds[t] = s;
    __syncthreads();
    if (t == 0) {
        int acc = 0;
        for (int i = 0; i < b; ++i) acc += pl[i];
        basePfx = acc;
    }
    for (int off = 1; off < SCAN_BLOCK; off <<= 1) {
        int val = (t >= off) ? lds[t - off] : 0;
        __syncthreads();
        lds[t] += val;
        __syncthreads();
    }
    int excl = (t == 0 ? 0 : lds[t - 1]) + basePfx;
#pragma unroll
    for (int k = 0; k < SCAN_ITEMS; ++k) {
        int i = base + k;
        if (i < N_NODES) {
            row_ptr[i] = excl;
            fill[i] = excl;
            dinv[i] = rsqrtf((float)(v[k] + 1));  // +1 self loop
            excl += v[k];
            if (i == N_NODES - 1) row_ptr[N_NODES] = excl;
        }
    }
}

// XCD-partitioned fill (R6 win). csr values ushort (src < 65536).
__global__ void k_fill_part(const int* __restrict__ src, const int* __restrict__ dst,
                            int* __restrict__ fill, unsigned short* __restrict__ csr, int E) {
    const int range = blockIdx.x & 7;
    const int stripe = blockIdx.x >> 3;
    const int lo = range * (N_NODES / 8);
    const int hi = lo + (N_NODES / 8);
    for (int e = stripe * 256 + threadIdx.x; e < E; e += FILL_STRIPES * 256) {
        int d = dst[e];
        if (d >= lo && d < hi) {
            int pos = atomicAdd(&fill[d], 1);
            csr[pos] = (unsigned short)src[e];
        }
    }
}

// ---------------- GEMM1: g̃(fp16) = dinv ⊙ (x @ W1) ----------------

__global__ __launch_bounds__(256) void k_gemm1(const float* __restrict__ A,
                                               const float* __restrict__ W,
                                               const float* __restrict__ dscale,
                                               __half* __restrict__ Cout, int N) {
    const int FIN = 128;
    __shared__ __align__(16) float As[64 * (FIN + 2)];
    __shared__ __align__(16) float Wsm[FIN * 64];
    const int t = threadIdx.x;
    const int row0 = blockIdx.x * 64;

    const int NF4 = 64 * FIN / 4;
    for (int idx = t; idx < NF4; idx += 256) {
        int r = idx / (FIN / 4);
        int c4 = idx % (FIN / 4);
        float4 v = make_float4(0.f, 0.f, 0.f, 0.f);
        if (row0 + r < N) v = ((const float4*)(A + (size_t)(row0 + r) * FIN))[c4];
        float* p = &As[r * (FIN + 2) + c4 * 4];
        ((float2*)p)[0] = make_float2(v.x, v.y);
        ((float2*)p)[1] = make_float2(v.z, v.w);
    }
    for (int idx = t; idx < FIN * 16; idx += 256) {
        int r = idx / 16, c4 = idx % 16;
        *((float4*)&Wsm[r * 64 + c4 * 4]) = ((const float4*)(W + (size_t)r * 64))[c4];
    }
    __syncthreads();

    const int tc = (t & 15) * 4;
    const int tr = (t >> 4) * 4;
    float acc[4][4] = {};
#pragma unroll 4
    for (int k = 0; k < FIN; k += 2) {
        float2 a[4];
#pragma unroll
        for (int r = 0; r < 4; ++r)
            a[r] = *(const float2*)&As[(tr + r) * (FIN + 2) + k];
        float4 w0 = *(const float4*)&Wsm[k * 64 + tc];
        float4 w1 = *(const float4*)&Wsm[(k + 1) * 64 + tc];
#pragma unroll
        for (int r = 0; r < 4; ++r) {
            acc[r][0] = fmaf(a[r].x, w0.x, acc[r][0]);
            acc[r][1] = fmaf(a[r].x, w0.y, acc[r][1]);
            acc[r][2] = fmaf(a[r].x, w0.z, acc[r][2]);
            acc[r][3] = fmaf(a[r].x, w0.w, acc[r][3]);
            acc[r][0] = fmaf(a[r].y, w1.x, acc[r][0]);
            acc[r][1] = fmaf(a[r].y, w1.y, acc[r][1]);
            acc[r][2] = fmaf(a[r].y, w1.z, acc[r][2]);
            acc[r][3] = fmaf(a[r].y, w1.w, acc[r][3]);
        }
    }

#pragma unroll
    for (int r = 0; r < 4; ++r) {
        int row = row0 + tr + r;
        if (row < N) {
            float s = dscale[row];
            __half2* dsth = (__half2*)(Cout + (size_t)row * 64 + tc);
            dsth[0] = __floats2half2_rn(acc[r][0] * s, acc[r][1] * s);
            dsth[1] = __floats2half2_rn(acc[r][2] * s, acc[r][3] * s);
        }
    }
}

// ---------------- aggregates: 16 lanes/node, 8 B per lane, 0 LDS ----------------
// h pre-scaled by dinv.
// RELU (conv1): out = fp16( dinv[n] * relu(bias + dinv[n]*sum) )   [h̃1]
// else (conv2): out = fp16( dinv[n] * sum )                         [z̃]

template <bool RELU>
__global__ void k_agg(const h4v* __restrict__ h, const float* __restrict__ dinv,
                      const int* __restrict__ row_ptr, const unsigned short* __restrict__ csr,
                      const float* __restrict__ bias, h4v* __restrict__ out, int N) {
    int node = blockIdx.x * 16 + (threadIdx.x >> 4);
    int lane = threadIdx.x & 15;
    if (node >= N) return;
    float di = dinv[node];
    h4v sv = h[(size_t)node * 16 + lane];  // self loop (pre-scaled)
    float2 pa = __half22float2(sv.a), pb = __half22float2(sv.b);
    float x0 = pa.x, y0 = pa.y, z0 = pb.x, w0 = pb.y;
    float x1 = 0, y1 = 0, z1 = 0, w1 = 0;
    float x2 = 0, y2 = 0, z2 = 0, w2 = 0;
    float x3 = 0, y3 = 0, z3 = 0, w3 = 0;
    int beg = row_ptr[node], end = row_ptr[node + 1];
    int j = beg;
    for (; j + 4 <= end; j += 4) {
        int s0 = csr[j], s1 = csr[j + 1], s2 = csr[j + 2], s3 = csr[j + 3];
        h4v v0 = h[(size_t)s0 * 16 + lane];
        h4v v1 = h[(size_t)s1 * 16 + lane];
        h4v v2 = h[(size_t)s2 * 16 + lane];
        h4v v3 = h[(size_t)s3 * 16 + lane];
        float2 a0 = __half22float2(v0.a), b0 = __half22float2(v0.b);
        float2 a1 = __half22float2(v1.a), b1 = __half22float2(v1.b);
        float2 a2 = __half22float2(v2.a), b2 = __half22float2(v2.b);
        float2 a3 = __half22float2(v3.a), b3 = __half22float2(v3.b);
        x0 += a0.x; y0 += a0.y; z0 += b0.x; w0 += b0.y;
        x1 += a1.x; y1 += a1.y; z1 += b1.x; w1 += b1.y;
        x2 += a2.x; y2 += a2.y; z2 += b2.x; w2 += b2.y;
        x3 += a3.x; y3 += a3.y; z3 += b3.x; w3 += b3.y;
    }
    for (; j < end; ++j) {
        h4v v = h[(size_t)csr[j] * 16 + lane];
        float2 a = __half22float2(v.a), b = __half22float2(v.b);
        x0 += a.x; y0 += a.y; z0 += b.x; w0 += b.y;
    }
    float sx = (x0 + x1) + (x2 + x3);
    float sy = (y0 + y1) + (y2 + y3);
    float sz = (z0 + z1) + (z2 + z3);
    float sw = (w0 + w1) + (w2 + w3);
    h4v o;
    if (RELU) {
        float4 bv = ((const float4*)bias)[lane];
        float vx = fmaf(sx, di, bv.x); vx = vx > 0.f ? vx : 0.f;
        float vy = fmaf(sy, di, bv.y); vy = vy > 0.f ? vy : 0.f;
        float vz = fmaf(sz, di, bv.z); vz = vz > 0.f ? vz : 0.f;
        float vw = fmaf(sw, di, bv.w); vw = vw > 0.f ? vw : 0.f;
        o.a = __floats2half2_rn(di * vx, di * vy);
        o.b = __floats2half2_rn(di * vz, di * vw);
    } else {
        o.a = __floats2half2_rn(sx * di, sy * di);
        o.b = __floats2half2_rn(sz * di, sw * di);
    }
    out[(size_t)node * 16 + lane] = o;
}

// ---------------- GEMM2 fused with mean-pool (two-pass structure) ----------------
// h2 = relu(z̃@W2 + b2) never materialized; per-tile per-graph LDS reduce + atomics.

__global__ __launch_bounds__(256) void k_gemm_pool(const __half2* __restrict__ A2,
                                                   const float* __restrict__ W,
                                                   const float* __restrict__ bias,
                                                   const int* __restrict__ batch,
                                                   float* __restrict__ sums, int N) {
    __shared__ __align__(16) float As[64 * 66];
    __shared__ __align__(16) float Wsm[64 * 64];
    __shared__ float red[16][68];
    __shared__ int batchLDS[64];
    const int t = threadIdx.x;
    const int row0 = blockIdx.x * 64;
    const int coff = blockIdx.y * 64;

    // stage A (fp16 -> fp32): 64 rows x 32 half2
    for (int idx = t; idx < 64 * 32; idx += 256) {
        int r = idx >> 5, c2 = idx & 31;
        float2 v = make_float2(0.f, 0.f);
        if (row0 + r < N) v = __half22float2(A2[(size_t)(row0 + r) * 32 + c2]);
        *(float2*)&As[r * 66 + c2 * 2] = v;
    }
    // stage W col slice (64 x 64 of [64,128])
    for (int idx = t; idx < 64 * 16; idx += 256) {
        int r = idx >> 4, c4 = idx & 15;
        *(float4*)&Wsm[r * 64 + c4 * 4] = *(const float4*)&W[(size_t)r * 128 + coff + c4 * 4];
    }
    if (t < 64) batchLDS[t] = batch[min(row0 + t, N - 1)];
    __syncthreads();

    const int tc = (t & 15) * 4;
    const int tr = (t >> 4) * 4;
    float acc[4][4] = {};
#pragma unroll 4
    for (int k = 0; k < 64; k += 2) {
        float2 a[4];
#pragma unroll
        for (int r = 0; r < 4; ++r)
            a[r] = *(const float2*)&As[(tr + r) * 66 + k];
        float4 w0 = *(const float4*)&Wsm[k * 64 + tc];
        float4 w1 = *(const float4*)&Wsm[(k + 1) * 64 + tc];
#pragma unroll
        for (int r = 0; r < 4; ++r) {
            acc[r][0] = fmaf(a[r].x, w0.x, acc[r][0]);
            acc[r][1] = fmaf(a[r].x, w0.y, acc[r][1]);
            acc[r][2] = fmaf(a[r].x, w0.z, acc[r][2]);
            acc[r][3] = fmaf(a[r].x, w0.w, acc[r][3]);
            acc[r][0] = fmaf(a[r].y, w1.x, acc[r][0]);
            acc[r][1] = fmaf(a[r].y, w1.y, acc[r][1]);
            acc[r][2] = fmaf(a[r].y, w1.z, acc[r][2]);
            acc[r][3] = fmaf(a[r].y, w1.w, acc[r][3]);
        }
    }

    // bias + relu; invalid rows contribute 0
    float4 bv = *(const float4*)&bias[coff + tc];
    float v[4][4];
#pragma unroll
    for (int r = 0; r < 4; ++r) {
        bool valid = (row0 + tr + r) < N;
        v[r][0] = valid ? fmaxf(acc[r][0] + bv.x, 0.f) : 0.f;
        v[r][1] = valid ? fmaxf(acc[r][1] + bv.y, 0.f) : 0.f;
        v[r][2] = valid ? fmaxf(acc[r][2] + bv.z, 0.f) : 0.f;
        v[r][3] = valid ? fmaxf(acc[r][3] + bv.w, 0.f) : 0.f;
    }

    const int g0 = batchLDS[0], g1 = batchLDS[63];
    const int trg = t >> 4;
    for (int g = g0; g <= g1; ++g) {
        float p0 = 0.f, p1 = 0.f, p2 = 0.f, p3 = 0.f;
#pragma unroll
        for (int r = 0; r < 4; ++r) {
            if (batchLDS[tr + r] == g) { p0 += v[r][0]; p1 += v[r][1]; p2 += v[r][2]; p3 += v[r][3]; }
        }
        red[trg][tc + 0] = p0; red[trg][tc + 1] = p1;
        red[trg][tc + 2] = p2; red[trg][tc + 3] = p3;
        __syncthreads();
        for (int off = 8; off > 0; off >>= 1) {
            if (trg < off) {
#pragma unroll
                for (int c = 0; c < 4; ++c) red[trg][tc + c] += red[trg + off][tc + c];
            }
            __syncthreads();
        }
        if (t < 16) {
#pragma unroll
            for (int c = 0; c < 4; ++c)
                atomicAdd(&sums[g * 128 + coff + t * 4 + c], red[0][t * 4 + c]);
        }
        __syncthreads();
    }
}

// ---------------- MLP head: one block per graph (cnt via binary search) ----------------

__global__ void k_mlp(const float* __restrict__ sums, const int* __restrict__ batch, int N,
                      const float* __restrict__ M1, const float* __restrict__ c1,
                      const float* __restrict__ M2, const float* __restrict__ c2,
                      const float* __restrict__ M3, const float* __restrict__ c3,
                      const float* __restrict__ M4, const float* __restrict__ c4,
                      float* __restrict__ out) {
    __shared__ float g[128], t1[64], t2[64], t3[64];
    __shared__ float cntb;
    int b = blockIdx.x;
    int t = threadIdx.x;
    if (t == 0) {
        int lo = 0, hi = N;
        while (lo < hi) { int m = (lo + hi) >> 1; if (batch[m] < b) lo = m + 1; else hi = m; }
        int lb = lo;
        lo = 0; hi = N;
        while (lo < hi) { int m = (lo + hi) >> 1; if (batch[m] <= b) lo = m + 1; else hi = m; }
        cntb = fmaxf((float)(lo - lb), 1.0f);
    }
    __syncthreads();
    if (t < 128) g[t] = sums[b * 128 + t] / cntb;
    __syncthreads();
    if (t < 64) {
        float acc = c1[t];
        for (int k = 0; k < 128; ++k) acc = fmaf(g[k], M1[k * 64 + t], acc);
        t1[t] = acc >= 0.f ? acc : 0.2f * acc;
    }
    __syncthreads();
    if (t < 64) {
        float acc = c2[t];
        for (int k = 0; k < 64; ++k) acc = fmaf(t1[k], M2[k * 64 + t], acc);
        t2[t] = acc >= 0.f ? acc : 0.1f * acc;
    }
    __syncthreads();
    if (t < 64) {
        float acc = c3[t];
        for (int k = 0; k < 64; ++k) acc = fmaf(t2[k], M3[k * 64 + t], acc);
        t3[t] = acc >= 0.f ? acc : 0.1f * acc;
    }
    __syncthreads();
    if (t == 0) {
        float acc = c4[0];
        for (int k = 0; k < 64; ++k) acc = fmaf(t3[k], M4[k], acc);
        out[b] = fmaxf(acc, 0.f);
    }
}

// ---------------- launch ----------------

extern "C" void kernel_launch(void* const* d_in, const int* in_sizes, int n_in,
                              void* d_out, int out_size, void* d_ws, size_t ws_size,
                              hipStream_t stream) {
    const float* x   = (const float*)d_in[0];
    const int*   ei  = (const int*)d_in[1];
    const int*   bat = (const int*)d_in[2];
    const float* W1  = (const float*)d_in[3];
    const float* b1  = (const float*)d_in[4];
    const float* W2  = (const float*)d_in[5];
    const float* b2  = (const float*)d_in[6];
    const float* M1  = (const float*)d_in[7];
    const float* c1  = (const float*)d_in[8];
    const float* M2  = (const float*)d_in[9];
    const float* c2  = (const float*)d_in[10];
    const float* M3  = (const float*)d_in[11];
    const float* c3  = (const float*)d_in[12];
    const float* M4  = (const float*)d_in[13];
    const float* c4  = (const float*)d_in[14];
    float* out = (float*)d_out;

    const int* src = ei;            // edge_index[0]
    const int* dst = ei + N_EDGES;  // edge_index[1]

    // workspace layout
    float* bufA    = (float*)d_ws;                          // g̃ / z̃: N*64 fp16
    float* bufB    = bufA + (size_t)N_NODES * 64;           // h̃1: N*64 fp16
    float* dinv    = bufB + (size_t)N_NODES * 64;           // N f
    float* sums    = dinv + N_NODES;                        // 64*128 f
    int*   deg     = (int*)(sums + N_GRAPHS * 128);         // N i
    int*   row_ptr = deg + N_NODES;                         // N+1 i
    int*   fill    = row_ptr + N_NODES + 1;                 // N i
    int*   part    = fill + N_NODES;                        // 64 i
    unsigned short* csr = (unsigned short*)(part + 64);     // E u16

    // ---- init + CSR build + normalization ----
    k_zero<<<(N_NODES + 255) / 256, 256, 0, stream>>>(deg, sums);
    k_deg_part<<<8 * FILL_STRIPES, 256, 0, stream>>>(dst, deg, N_EDGES);
    k_scan1<<<NB_SCAN, SCAN_BLOCK, 0, stream>>>(deg, part);
    k_scan3<<<NB_SCAN, SCAN_BLOCK, 0, stream>>>(deg, part, row_ptr, fill, dinv);
    k_fill_part<<<8 * FILL_STRIPES, 256, 0, stream>>>(src, dst, fill, csr, N_EDGES);

    const int NBLK = (N_NODES + 63) / 64;   // 782
    const int ABLK = (N_NODES + 15) / 16;   // 3125

    // ---- conv1: g̃(fp16) = dinv ⊙ (x@W1); h̃1(fp16) = dinv ⊙ relu(Â-sum + b1) ----
    k_gemm1<<<NBLK, 256, 0, stream>>>(x, W1, dinv, (__half*)bufA, N_NODES);
    k_agg<true><<<ABLK, 256, 0, stream>>>(
        (const h4v*)bufA, dinv, row_ptr, csr, b1, (h4v*)bufB, N_NODES);

    // ---- conv2: z̃(fp16) = dinv ⊙ (Σ h̃1); two-pass gemm2+relu+mean-pool ----
    k_agg<false><<<ABLK, 256, 0, stream>>>(
        (const h4v*)bufB, dinv, row_ptr, csr, nullptr, (h4v*)bufA, N_NODES);
    k_gemm_pool<<<dim3(NBLK, 2), 256, 0, stream>>>(
        (const __half2*)bufA, W2, b2, bat, sums, N_NODES);

    // ---- MLP ----
    k_mlp<<<N_GRAPHS, 128, 0, stream>>>(sums, bat, N_NODES,
                                        M1, c1, M2, c2, M3, c3, M4, c4, out);
}